// Round 4
// baseline (406.317 us; speedup 1.0000x reference)
//
#include <hip/hip_runtime.h>

constexpr int NN = 100000;   // nodes
constexpr int DI = 256;      // in features
constexpr int DO = 128;      // out features
constexpr int NE = 1600000;  // edges

constexpr int BROWS = 128;                        // rows per bucket
constexpr int NBK   = (NN + BROWS - 1) / BROWS;   // 782 buckets
constexpr int TILE  = 8192;                       // edges per partition block
constexpr int CAP   = 2688;                       // slots per bucket (mean 2046, sd ~45)

typedef __bf16 bf16x8 __attribute__((ext_vector_type(8)));
typedef float  f32x4  __attribute__((ext_vector_type(4)));

__device__ inline unsigned short f2bf(float f) {
    union { float f; unsigned u; } v; v.f = f;
    return (unsigned short)((v.u + 0x7FFF + ((v.u >> 16) & 1)) >> 16);
}
__device__ inline float bf2f(unsigned u16) {
    union { unsigned u; float f; } v; v.u = u16 << 16;
    return v.f;
}

// ---------------- W transpose: W[256][128] f32 -> Wt[128][256] bf16 ----------
__global__ __launch_bounds__(256)
void wt_kernel(const float* __restrict__ W, unsigned short* __restrict__ Wt) {
    __shared__ float t[32][33];
    const int tx = threadIdx.x & 31, ty = threadIdx.x >> 5;
    const int k0 = (blockIdx.x >> 2) * 32, n0 = (blockIdx.x & 3) * 32;
#pragma unroll
    for (int i = 0; i < 32; i += 8)
        t[ty + i][tx] = W[(size_t)(k0 + ty + i) * DO + n0 + tx];
    __syncthreads();
#pragma unroll
    for (int i = 0; i < 32; i += 8)
        Wt[(size_t)(n0 + ty + i) * DI + k0 + tx] = f2bf(t[tx][ty + i]);
}

// ---------------- GEMM: h = bf16( (x*mask) @ W ), deep-burst A loads --------
// Post-mortem R3: barrier-free version was latency-bound at VGPR=68 — the
// compiler serialized into short load->wait->MFMA segments (~1-2 outstanding
// 1KB wave-loads; need ~9KB/CU in flight for 6.3 TB/s). Fix: each wave
// burst-issues HALF its A panel (16 independent 16B loads/lane = 16KB/wave
// in flight), converts, bursts the other half, then runs the MFMA tail.
// __launch_bounds__(256,3) -> 170 VGPR so all 16 load destinations stay
// live; 12 waves/CU x 16KB = ~192KB outstanding per CU.
union BF8 { bf16x8 v; unsigned short u[8]; };

__device__ inline bf16x8 mk8(const float4& a, const float4& b,
                             const float4& ma, const float4& mb) {
    BF8 r;
    r.u[0] = f2bf(a.x * ma.x); r.u[1] = f2bf(a.y * ma.y);
    r.u[2] = f2bf(a.z * ma.z); r.u[3] = f2bf(a.w * ma.w);
    r.u[4] = f2bf(b.x * mb.x); r.u[5] = f2bf(b.y * mb.y);
    r.u[6] = f2bf(b.z * mb.z); r.u[7] = f2bf(b.w * mb.w);
    return r.v;
}

__global__ __launch_bounds__(256, 3)
void gemm_kernel(const float* __restrict__ x, const float* __restrict__ mask,
                 const unsigned short* __restrict__ Wt,
                 unsigned short* __restrict__ h) {
    const int tid  = threadIdx.x;
    const int lane = tid & 63;
    const int w    = tid >> 6;          // wave 0..3
    const int m0   = blockIdx.x * 64;
    const int mw   = w * 16;            // wave's 16-row slice
    const int l15  = lane & 15;
    const int l4   = lane >> 4;

    // this lane's A row (clamped for the grid tail; stores are guarded)
    const int arow = m0 + mw + l15;
    const size_t rbase = (size_t)(arow < NN ? arow : 0) * DI + l4 * 8;
    const float4* xp = (const float4*)(x + rbase);     // float4 index i = 4*i floats
    const float4* mp = (const float4*)(mask + rbase);

    f32x4 acc[8];
#pragma unroll
    for (int ct = 0; ct < 8; ++ct) acc[ct] = (f32x4){0.f, 0.f, 0.f, 0.f};

    // Half-panel burst: K-steps {S,S+1}; float4 indices S*16 + {0,1,8,9,16,17,24,25}
    float4 xr[8], mr[8];
#define LOADH(S)                                                       \
    do {                                                               \
        const int o = (S) * 16;                                        \
        xr[0] = xp[o + 0];  xr[1] = xp[o + 1];                         \
        xr[2] = xp[o + 8];  xr[3] = xp[o + 9];                         \
        xr[4] = xp[o + 16]; xr[5] = xp[o + 17];                        \
        xr[6] = xp[o + 24]; xr[7] = xp[o + 25];                        \
        mr[0] = mp[o + 0];  mr[1] = mp[o + 1];                         \
        mr[2] = mp[o + 8];  mr[3] = mp[o + 9];                         \
        mr[4] = mp[o + 16]; mr[5] = mp[o + 17];                        \
        mr[6] = mp[o + 24]; mr[7] = mp[o + 25];                        \
    } while (0)

    bf16x8 af[4];   // fragments for 2 K-steps: af[2*s + ks]
#define CONV()                                                         \
    do {                                                               \
        af[0] = mk8(xr[0], xr[1], mr[0], mr[1]);                       \
        af[1] = mk8(xr[2], xr[3], mr[2], mr[3]);                       \
        af[2] = mk8(xr[4], xr[5], mr[4], mr[5]);                       \
        af[3] = mk8(xr[6], xr[7], mr[6], mr[7]);                       \
    } while (0)

    // MFMA for the two K-steps held in af[]; base K offset = KB (floats)
#define MFMA2(KB)                                                      \
    do {                                                               \
        _Pragma("unroll")                                              \
        for (int s = 0; s < 2; ++s) {                                  \
            const int kc = (KB) + s * 64;                              \
            _Pragma("unroll")                                          \
            for (int ct = 0; ct < 8; ++ct) {                           \
                const unsigned short* bp =                             \
                    Wt + (size_t)(ct * 16 + l15) * DI + kc + l4 * 8;   \
                const bf16x8 b0 = *(const bf16x8*)(bp);                \
                const bf16x8 b1 = *(const bf16x8*)(bp + 32);           \
                acc[ct] = __builtin_amdgcn_mfma_f32_16x16x32_bf16(     \
                    af[2 * s], b0, acc[ct], 0, 0, 0);                  \
                acc[ct] = __builtin_amdgcn_mfma_f32_16x16x32_bf16(     \
                    af[2 * s + 1], b1, acc[ct], 0, 0, 0);              \
            }                                                          \
        }                                                              \
    } while (0)

    LOADH(0);        // 16 loads in flight (K-steps 0,1)
    CONV();          // waits as results arrive; xr/mr die
    LOADH(2);        // next 16 loads in flight (K-steps 2,3) -- overlap MFMA
    MFMA2(0);        // B loads (L2-hot) + MFMA for K-steps 0,1
    CONV();          // convert K-steps 2,3
    MFMA2(128);      // K-steps 2,3

#undef LOADH
#undef CONV
#undef MFMA2

    // epilogue: D[row = l4*4+reg][col = l15]
#pragma unroll
    for (int ct = 0; ct < 8; ++ct)
#pragma unroll
        for (int reg = 0; reg < 4; ++reg) {
            const int row = m0 + mw + l4 * 4 + reg;
            if (row < NN)
                h[(size_t)row * DO + ct * 16 + l15] = f2bf(acc[ct][reg]);
        }
}

// ---------------- partition: edges -> fixed-slot bucket lists ---------------
// csr[b*CAP + i]; global bcnt is both cursor and final per-bucket count.
__global__ __launch_bounds__(256)
void part_kernel(const int* __restrict__ erow, const int* __restrict__ ecol,
                 const float* __restrict__ ew, int* __restrict__ bcnt,
                 int2* __restrict__ csr) {
    __shared__ int cnt[NBK];
    __shared__ int base[NBK];
    const int t  = threadIdx.x;
    const int e0 = blockIdx.x * TILE;
    for (int k = t; k < NBK; k += 256) cnt[k] = 0;
    __syncthreads();
    for (int k = 0; k < TILE; k += 256) {
        const int e = e0 + k + t;
        if (e < NE) atomicAdd(&cnt[erow[e] >> 7], 1);
    }
    __syncthreads();
    for (int k = t; k < NBK; k += 256) {
        const int c = cnt[k];
        base[k] = c ? atomicAdd(&bcnt[k], c) : 0;
        cnt[k] = 0;
    }
    __syncthreads();
    for (int k = 0; k < TILE; k += 256) {
        const int e = e0 + k + t;
        if (e < NE) {
            const int row = erow[e];
            const int bk  = row >> 7;
            const int pos = atomicAdd(&cnt[bk], 1);
            int2 v;
            v.x = ((row & 127) << 17) | ecol[e];   // col < 2^17
            v.y = __float_as_int(ew[e]);
            csr[(size_t)bk * CAP + base[bk] + pos] = v;
        }
    }
}

// ---------------- bucket gather: LDS counting sort + register gather --------
// 512 threads/block (grid fixed at 782 -> 3 blocks/CU; wider block = more
// resident waves for latency hiding on random h reads).
__global__ __launch_bounds__(512)
void bgather_kernel(const unsigned short* __restrict__ h,
                    const int* __restrict__ bcnt,
                    const int2* __restrict__ csr, float* __restrict__ out) {
    __shared__ int2 se[CAP];            // sorted edges
    __shared__ int  s_cnt[BROWS];       // histogram -> cursor
    __shared__ int  s_start[BROWS + 1];
    __shared__ int  wtot;
    const int b = blockIdx.x, t = threadIdx.x;
    const int n = bcnt[b];
    const int2* ebase = csr + (size_t)b * CAP;

    if (t < BROWS) s_cnt[t] = 0;
    __syncthreads();
    // pass 1: histogram by row-offset
    for (int j = t; j < n; j += 512)
        atomicAdd(&s_cnt[((unsigned)ebase[j].x) >> 17], 1);
    __syncthreads();
    // scan 128 bins
    const int lane = t & 63;
    int c = 0;
    if (t < BROWS) c = s_cnt[t];
    int v = c;
#pragma unroll
    for (int off = 1; off < 64; off <<= 1) {
        const int nn = __shfl_up(v, off, 64);
        if (lane >= off) v += nn;
    }
    if (t == 63) wtot = v;
    __syncthreads();
    if (t < BROWS) {
        const int excl = v - c + (t >= 64 ? wtot : 0);
        s_start[t] = excl;
        s_cnt[t]   = excl;   // reuse as scatter cursor
    }
    if (t == 0) s_start[BROWS] = n;
    __syncthreads();
    // pass 2: scatter into row-sorted order
    for (int j = t; j < n; j += 512) {
        const int2 cw  = ebase[j];
        const int  pos = atomicAdd(&s_cnt[((unsigned)cw.x) >> 17], 1);
        se[pos] = cw;
    }
    __syncthreads();

    // gather: 32 groups of 16 lanes; group g handles rows g, g+32, g+64, g+96
    const int l16 = t & 15, g = t >> 4;
    const int row0 = b * BROWS;
#pragma unroll
    for (int rp = 0; rp < 4; ++rp) {
        const int r  = rp * 32 + g;
        const int gr = row0 + r;
        const int rs = s_start[r], re = s_start[r + 1];
        float acc[8];
#pragma unroll
        for (int i = 0; i < 8; ++i) acc[i] = 0.f;
        int j = rs;
        for (; j + 2 <= re; j += 2) {
            const int2 cw0 = se[j], cw1 = se[j + 1];
            const float w0 = __int_as_float(cw0.y);
            const float w1 = __int_as_float(cw1.y);
            const uint4 q0 = *(const uint4*)(h + (size_t)(cw0.x & 0x1FFFF) * DO + l16 * 8);
            const uint4 q1 = *(const uint4*)(h + (size_t)(cw1.x & 0x1FFFF) * DO + l16 * 8);
            const unsigned* u0 = (const unsigned*)&q0;
            const unsigned* u1 = (const unsigned*)&q1;
#pragma unroll
            for (int i = 0; i < 4; ++i) {
                acc[2 * i + 0] += w0 * bf2f(u0[i] & 0xFFFF) + w1 * bf2f(u1[i] & 0xFFFF);
                acc[2 * i + 1] += w0 * bf2f(u0[i] >> 16)    + w1 * bf2f(u1[i] >> 16);
            }
        }
        if (j < re) {
            const int2 cw = se[j];
            const float w = __int_as_float(cw.y);
            const uint4 q = *(const uint4*)(h + (size_t)(cw.x & 0x1FFFF) * DO + l16 * 8);
            const unsigned* u = (const unsigned*)&q;
#pragma unroll
            for (int i = 0; i < 4; ++i) {
                acc[2 * i + 0] += w * bf2f(u[i] & 0xFFFF);
                acc[2 * i + 1] += w * bf2f(u[i] >> 16);
            }
        }
        if (gr < NN) {
            float* op = out + (size_t)gr * DO + l16 * 8;
            *(float4*)(op + 0) = make_float4(fmaxf(acc[0], 0.f), fmaxf(acc[1], 0.f),
                                             fmaxf(acc[2], 0.f), fmaxf(acc[3], 0.f));
            *(float4*)(op + 4) = make_float4(fmaxf(acc[4], 0.f), fmaxf(acc[5], 0.f),
                                             fmaxf(acc[6], 0.f), fmaxf(acc[7], 0.f));
        }
    }
}

extern "C" void kernel_launch(void* const* d_in, const int* in_sizes, int n_in,
                              void* d_out, int out_size, void* d_ws, size_t ws_size,
                              hipStream_t stream) {
    const float* x    = (const float*)d_in[0];
    const float* mask = (const float*)d_in[1];
    const float* W    = (const float*)d_in[2];
    const int*   erow = (const int*)d_in[3];
    const int*   ecol = (const int*)d_in[4];
    const float* ew   = (const float*)d_in[5];
    float* out = (float*)d_out;

    char* p = (char*)d_ws;
    unsigned short* h  = (unsigned short*)p;  p += (size_t)NN * DO * 2;   // 25.6 MB
    unsigned short* Wt = (unsigned short*)p;  p += (size_t)DO * DI * 2;   // 64 KB
    int* bcnt = (int*)p;                      p += 3200;
    int2* csr = (int2*)p;                     // NBK*CAP*8 = 16.8 MB

    hipMemsetAsync(bcnt, 0, NBK * sizeof(int), stream);

    wt_kernel<<<32, 256, 0, stream>>>(W, Wt);
    gemm_kernel<<<(NN + 63) / 64, 256, 0, stream>>>(x, mask, Wt, h);
    part_kernel<<<(NE + TILE - 1) / TILE, 256, 0, stream>>>(erow, ecol, ew,
                                                            bcnt, csr);
    bgather_kernel<<<NBK, 512, 0, stream>>>(h, bcnt, csr, out);
}

// Round 5
// 405.541 us; speedup vs baseline: 1.0019x; 1.0019x over previous
//
#include <hip/hip_runtime.h>

constexpr int NN = 100000;   // nodes
constexpr int DI = 256;      // in features
constexpr int DO = 128;      // out features
constexpr int NE = 1600000;  // edges

constexpr int BROWS = 128;                        // rows per bucket
constexpr int NBK   = (NN + BROWS - 1) / BROWS;   // 782 buckets
constexpr int TILE  = 8192;                       // edges per partition block
constexpr int CAP   = 2688;                       // slots per bucket (mean 2046, sd ~45)

typedef __bf16 bf16x8 __attribute__((ext_vector_type(8)));
typedef float  f32x4  __attribute__((ext_vector_type(4)));

__device__ inline unsigned short f2bf(float f) {
    union { float f; unsigned u; } v; v.f = f;
    return (unsigned short)((v.u + 0x7FFF + ((v.u >> 16) & 1)) >> 16);
}
__device__ inline float bf2f(unsigned u16) {
    union { unsigned u; float f; } v; v.u = u16 << 16;
    return v.f;
}

// ---------------- W transpose: W[256][128] f32 -> Wt[128][256] bf16 ----------
__global__ __launch_bounds__(256)
void wt_kernel(const float* __restrict__ W, unsigned short* __restrict__ Wt) {
    __shared__ float t[32][33];
    const int tx = threadIdx.x & 31, ty = threadIdx.x >> 5;
    const int k0 = (blockIdx.x >> 2) * 32, n0 = (blockIdx.x & 3) * 32;
#pragma unroll
    for (int i = 0; i < 32; i += 8)
        t[ty + i][tx] = W[(size_t)(k0 + ty + i) * DO + n0 + tx];
    __syncthreads();
#pragma unroll
    for (int i = 0; i < 32; i += 8)
        Wt[(size_t)(n0 + ty + i) * DI + k0 + tx] = f2bf(t[tx][ty + i]);
}

// ---------------- GEMM: h = bf16( (x*mask) @ W ), async DMA staging ---------
// Post-mortem R4: compiler refuses deep VGPR load pipelines (VGPR 68->56
// across two attempts; ~2 loads in flight -> 1.2 TB/s latency-bound).
// Fix: global_load_lds DMA (no VGPR destinations -> compiler cannot
// serialize). Each wave stages ITS OWN 16 rows of x,m (f32) into LDS,
// double-buffered across named arrays, 8x16B DMA per wave per K-step =
// 8 KB/wave guaranteed in flight; zero barriers (no cross-wave data flow).
// LDS row stride 256B would be a 16-way bank conflict on ds_read_b128, so
// stage pre-swizzles the GLOBAL source chunk (c ^= row&7) and reads apply
// the same XOR (dest stays linear as DMA requires).
union BF8 { bf16x8 v; unsigned short u[8]; };

__device__ inline bf16x8 mk8(const float4& a, const float4& b,
                             const float4& ma, const float4& mb) {
    BF8 r;
    r.u[0] = f2bf(a.x * ma.x); r.u[1] = f2bf(a.y * ma.y);
    r.u[2] = f2bf(a.z * ma.z); r.u[3] = f2bf(a.w * ma.w);
    r.u[4] = f2bf(b.x * mb.x); r.u[5] = f2bf(b.y * mb.y);
    r.u[6] = f2bf(b.z * mb.z); r.u[7] = f2bf(b.w * mb.w);
    return r.v;
}

__device__ inline void gload_lds16(const float* g, float* l) {
    __builtin_amdgcn_global_load_lds(
        (const __attribute__((address_space(1))) void*)(g),
        (__attribute__((address_space(3))) void*)(l), 16, 0, 0);
}

__global__ __launch_bounds__(256)
void gemm_kernel(const float* __restrict__ x, const float* __restrict__ mask,
                 const unsigned short* __restrict__ Wt,
                 unsigned short* __restrict__ h) {
    __shared__ float sxA[64][64], smA[64][64];   // K-tile buffers (f32)
    __shared__ float sxB[64][64], smB[64][64];   // 4 x 16 KB = 64 KB
    const int tid  = threadIdx.x;
    const int lane = tid & 63;
    const int w    = tid >> 6;          // wave 0..3
    const int m0   = blockIdx.x * 64;
    const int mw   = w * 16;            // wave's 16-row slice
    const int l15  = lane & 15;
    const int l4   = lane >> 4;
    const int row  = mw + l15;          // LDS row this lane consumes
    const int rx   = row & 7;           // read-side swizzle key

    f32x4 acc[8];
#pragma unroll
    for (int ct = 0; ct < 8; ++ct) acc[ct] = (f32x4){0.f, 0.f, 0.f, 0.f};

    // Wave w stages rows mw..mw+15 (the rows it consumes). DMA dest is
    // wave-uniform (&S[mw+j*4][0]); HW writes lane*16B -> linear rows.
    // Source chunk pre-swizzled so LDS[r][c] = G[r][c ^ (r&7)].
#define STAGE(SX, SM, K0)                                                  \
    do {                                                                   \
        _Pragma("unroll")                                                  \
        for (int j = 0; j < 4; ++j) {                                      \
            const int rr = mw + j * 4 + (lane >> 4);                       \
            const int cs = ((lane & 15) ^ (rr & 7)) * 4;                   \
            int grow = m0 + rr; if (grow >= NN) grow = NN - 1;             \
            const size_t go = (size_t)grow * DI + (K0) + cs;               \
            gload_lds16(x + go,    &SX[mw + j * 4][0]);                    \
            gload_lds16(mask + go, &SM[mw + j * 4][0]);                    \
        }                                                                  \
    } while (0)

    // One 64-wide K-step from buffers (SX,SM) at global K offset KC.
#define STEP(SX, SM, KC)                                                   \
    do {                                                                   \
        _Pragma("unroll")                                                  \
        for (int ks = 0; ks < 2; ++ks) {                                   \
            const int c0 = ks * 8 + l4 * 2;                                \
            const float4 xa = *(const float4*)&SX[row][((c0    ) ^ rx)*4]; \
            const float4 xb = *(const float4*)&SX[row][((c0 + 1) ^ rx)*4]; \
            const float4 na = *(const float4*)&SM[row][((c0    ) ^ rx)*4]; \
            const float4 nb = *(const float4*)&SM[row][((c0 + 1) ^ rx)*4]; \
            const bf16x8 a = mk8(xa, xb, na, nb);                          \
            _Pragma("unroll")                                              \
            for (int ct = 0; ct < 8; ++ct) {                               \
                const bf16x8 b = *(const bf16x8*)(Wt +                     \
                    (size_t)(ct * 16 + l15) * DI + (KC) + ks * 32 + l4*8); \
                acc[ct] = __builtin_amdgcn_mfma_f32_16x16x32_bf16(         \
                    a, b, acc[ct], 0, 0, 0);                               \
            }                                                              \
        }                                                                  \
    } while (0)

    STAGE(sxA, smA, 0);      // 8 DMA in flight
    STAGE(sxB, smB, 64);     // 16 DMA in flight
    STEP(sxA, smA, 0);       // waits A (oldest 8); B still flying
    STAGE(sxA, smA, 128);    // reuse A buffer (this wave done with it)
    STEP(sxB, smB, 64);
    STAGE(sxB, smB, 192);
    STEP(sxA, smA, 128);
    STEP(sxB, smB, 192);

#undef STAGE
#undef STEP

    // epilogue: D[row = l4*4+reg][col = l15]
#pragma unroll
    for (int ct = 0; ct < 8; ++ct)
#pragma unroll
        for (int reg = 0; reg < 4; ++reg) {
            const int r = m0 + mw + l4 * 4 + reg;
            if (r < NN)
                h[(size_t)r * DO + ct * 16 + l15] = f2bf(acc[ct][reg]);
        }
}

// ---------------- partition: edges -> fixed-slot bucket lists ---------------
// csr[b*CAP + i]; global bcnt is both cursor and final per-bucket count.
__global__ __launch_bounds__(256)
void part_kernel(const int* __restrict__ erow, const int* __restrict__ ecol,
                 const float* __restrict__ ew, int* __restrict__ bcnt,
                 int2* __restrict__ csr) {
    __shared__ int cnt[NBK];
    __shared__ int base[NBK];
    const int t  = threadIdx.x;
    const int e0 = blockIdx.x * TILE;
    for (int k = t; k < NBK; k += 256) cnt[k] = 0;
    __syncthreads();
    for (int k = 0; k < TILE; k += 256) {
        const int e = e0 + k + t;
        if (e < NE) atomicAdd(&cnt[erow[e] >> 7], 1);
    }
    __syncthreads();
    for (int k = t; k < NBK; k += 256) {
        const int c = cnt[k];
        base[k] = c ? atomicAdd(&bcnt[k], c) : 0;
        cnt[k] = 0;
    }
    __syncthreads();
    for (int k = 0; k < TILE; k += 256) {
        const int e = e0 + k + t;
        if (e < NE) {
            const int row = erow[e];
            const int bk  = row >> 7;
            const int pos = atomicAdd(&cnt[bk], 1);
            int2 v;
            v.x = ((row & 127) << 17) | ecol[e];   // col < 2^17
            v.y = __float_as_int(ew[e]);
            csr[(size_t)bk * CAP + base[bk] + pos] = v;
        }
    }
}

// ---------------- bucket gather: LDS counting sort + register gather --------
// 512 threads/block (grid fixed at 782 -> 3 blocks/CU; wider block = more
// resident waves for latency hiding on random h reads).
__global__ __launch_bounds__(512)
void bgather_kernel(const unsigned short* __restrict__ h,
                    const int* __restrict__ bcnt,
                    const int2* __restrict__ csr, float* __restrict__ out) {
    __shared__ int2 se[CAP];            // sorted edges
    __shared__ int  s_cnt[BROWS];       // histogram -> cursor
    __shared__ int  s_start[BROWS + 1];
    __shared__ int  wtot;
    const int b = blockIdx.x, t = threadIdx.x;
    const int n = bcnt[b];
    const int2* ebase = csr + (size_t)b * CAP;

    if (t < BROWS) s_cnt[t] = 0;
    __syncthreads();
    // pass 1: histogram by row-offset
    for (int j = t; j < n; j += 512)
        atomicAdd(&s_cnt[((unsigned)ebase[j].x) >> 17], 1);
    __syncthreads();
    // scan 128 bins
    const int lane = t & 63;
    int c = 0;
    if (t < BROWS) c = s_cnt[t];
    int v = c;
#pragma unroll
    for (int off = 1; off < 64; off <<= 1) {
        const int nn = __shfl_up(v, off, 64);
        if (lane >= off) v += nn;
    }
    if (t == 63) wtot = v;
    __syncthreads();
    if (t < BROWS) {
        const int excl = v - c + (t >= 64 ? wtot : 0);
        s_start[t] = excl;
        s_cnt[t]   = excl;   // reuse as scatter cursor
    }
    if (t == 0) s_start[BROWS] = n;
    __syncthreads();
    // pass 2: scatter into row-sorted order
    for (int j = t; j < n; j += 512) {
        const int2 cw  = ebase[j];
        const int  pos = atomicAdd(&s_cnt[((unsigned)cw.x) >> 17], 1);
        se[pos] = cw;
    }
    __syncthreads();

    // gather: 32 groups of 16 lanes; group g handles rows g, g+32, g+64, g+96
    const int l16 = t & 15, g = t >> 4;
    const int row0 = b * BROWS;
#pragma unroll
    for (int rp = 0; rp < 4; ++rp) {
        const int r  = rp * 32 + g;
        const int gr = row0 + r;
        const int rs = s_start[r], re = s_start[r + 1];
        float acc[8];
#pragma unroll
        for (int i = 0; i < 8; ++i) acc[i] = 0.f;
        int j = rs;
        for (; j + 2 <= re; j += 2) {
            const int2 cw0 = se[j], cw1 = se[j + 1];
            const float w0 = __int_as_float(cw0.y);
            const float w1 = __int_as_float(cw1.y);
            const uint4 q0 = *(const uint4*)(h + (size_t)(cw0.x & 0x1FFFF) * DO + l16 * 8);
            const uint4 q1 = *(const uint4*)(h + (size_t)(cw1.x & 0x1FFFF) * DO + l16 * 8);
            const unsigned* u0 = (const unsigned*)&q0;
            const unsigned* u1 = (const unsigned*)&q1;
#pragma unroll
            for (int i = 0; i < 4; ++i) {
                acc[2 * i + 0] += w0 * bf2f(u0[i] & 0xFFFF) + w1 * bf2f(u1[i] & 0xFFFF);
                acc[2 * i + 1] += w0 * bf2f(u0[i] >> 16)    + w1 * bf2f(u1[i] >> 16);
            }
        }
        if (j < re) {
            const int2 cw = se[j];
            const float w = __int_as_float(cw.y);
            const uint4 q = *(const uint4*)(h + (size_t)(cw.x & 0x1FFFF) * DO + l16 * 8);
            const unsigned* u = (const unsigned*)&q;
#pragma unroll
            for (int i = 0; i < 4; ++i) {
                acc[2 * i + 0] += w * bf2f(u[i] & 0xFFFF);
                acc[2 * i + 1] += w * bf2f(u[i] >> 16);
            }
        }
        if (gr < NN) {
            float* op = out + (size_t)gr * DO + l16 * 8;
            *(float4*)(op + 0) = make_float4(fmaxf(acc[0], 0.f), fmaxf(acc[1], 0.f),
                                             fmaxf(acc[2], 0.f), fmaxf(acc[3], 0.f));
            *(float4*)(op + 4) = make_float4(fmaxf(acc[4], 0.f), fmaxf(acc[5], 0.f),
                                             fmaxf(acc[6], 0.f), fmaxf(acc[7], 0.f));
        }
    }
}

extern "C" void kernel_launch(void* const* d_in, const int* in_sizes, int n_in,
                              void* d_out, int out_size, void* d_ws, size_t ws_size,
                              hipStream_t stream) {
    const float* x    = (const float*)d_in[0];
    const float* mask = (const float*)d_in[1];
    const float* W    = (const float*)d_in[2];
    const int*   erow = (const int*)d_in[3];
    const int*   ecol = (const int*)d_in[4];
    const float* ew   = (const float*)d_in[5];
    float* out = (float*)d_out;

    char* p = (char*)d_ws;
    unsigned short* h  = (unsigned short*)p;  p += (size_t)NN * DO * 2;   // 25.6 MB
    unsigned short* Wt = (unsigned short*)p;  p += (size_t)DO * DI * 2;   // 64 KB
    int* bcnt = (int*)p;                      p += 3200;
    int2* csr = (int2*)p;                     // NBK*CAP*8 = 16.8 MB

    hipMemsetAsync(bcnt, 0, NBK * sizeof(int), stream);

    wt_kernel<<<32, 256, 0, stream>>>(W, Wt);
    gemm_kernel<<<(NN + 63) / 64, 256, 0, stream>>>(x, mask, Wt, h);
    part_kernel<<<(NE + TILE - 1) / TILE, 256, 0, stream>>>(erow, ecol, ew,
                                                            bcnt, csr);
    bgather_kernel<<<NBK, 512, 0, stream>>>(h, bcnt, csr, out);
}